// Round 7
// baseline (492.176 us; speedup 1.0000x reference)
//
#include <hip/hip_runtime.h>

#define N_NODES  50000
#define N_EDGES  800000
#define HID      128
#define OUT_C    16
#define N_GRAPHS 128
#define MAXDEG   64     // Poisson(16): P(deg>=64) ~ 1e-19/node — clamped anyway
#define WIN      200    // nodes per fill window; 250 blocks exactly cover 50000

typedef __attribute__((ext_vector_type(8))) short bf16x8;
typedef __attribute__((ext_vector_type(4))) float f32x4;
typedef __attribute__((ext_vector_type(8))) unsigned short us8;
typedef __attribute__((ext_vector_type(4))) unsigned short us4;

__device__ __forceinline__ unsigned short f2bf(float f) {
  unsigned u = __float_as_uint(f);
  u += 0x7fffu + ((u >> 16) & 1u);   // RNE
  return (unsigned short)(u >> 16);
}

// ---------------- dst -> ushort compaction (halves scan bytes) ----------------
__global__ __launch_bounds__(256) void compact_kernel(
    const int* __restrict__ dst, unsigned short* __restrict__ dst16) {
  int i = blockIdx.x * 256 + threadIdx.x;     // one int4 -> us4
  if (i < N_EDGES / 4) {
    int4 d = ((const int4*)dst)[i];
    us4 o;
    o.x = (unsigned short)d.x; o.y = (unsigned short)d.y;
    o.z = (unsigned short)d.z; o.w = (unsigned short)d.w;
    *(us4*)(dst16 + i * 4) = o;
  }
}

// ---------------- window-scan ELL fill: adjacency built entirely in LDS ------
// Round-6 counters: global-scattered builds churn dirty lines in L2 (29 MB
// write-back for a 6.6 MB structure). Here each block exclusively owns 200
// nodes, scans the (L2-resident, ushort-compacted) dst stream, LDS-atomics
// its matches, then writes deg+ELL coalesced exactly once.
__global__ __launch_bounds__(256) void fill_win_kernel(
    const int* __restrict__ src, const unsigned short* __restrict__ dst16,
    int* __restrict__ deg, unsigned short* __restrict__ ell) {
  __shared__ unsigned short sell[WIN * MAXDEG];   // 25.6 KB
  __shared__ int sdeg[WIN];
  const int n0 = blockIdx.x * WIN;
  for (int i = threadIdx.x; i < WIN; i += 256) sdeg[i] = 0;
  __syncthreads();
  const us8* __restrict__ d8 = (const us8*)dst16;
  for (int q = threadIdx.x; q < N_EDGES / 8; q += 256) {
    us8 d = d8[q];
    int e = q * 8;
#pragma unroll
    for (int j = 0; j < 8; ++j) {
      unsigned r = (unsigned)((int)d[j] - n0);
      if (r < (unsigned)WIN) {
        int p = atomicAdd(&sdeg[r], 1);
        if (p < MAXDEG) sell[(r << 6) + p] = (unsigned short)src[e + j];
      }
    }
  }
  __syncthreads();
  for (int i = threadIdx.x; i < WIN; i += 256) {
    int n = n0 + i;
    if (n < N_NODES) deg[n] = sdeg[i];
  }
  us8* __restrict__ eo = (us8*)(ell + (size_t)n0 * MAXDEG);
  const us8* __restrict__ ei8 = (const us8*)sell;
  for (int i = threadIdx.x; i < WIN * MAXDEG / 8; i += 256)
    eo[i] = ei8[i];   // slots beyond deg are never read
}

// ---------------- fused prep: Wt transpose+bf16 | deg_inv_sqrt | bounds -----
__global__ void prep_kernel(const float* __restrict__ W1, const float* __restrict__ W2,
                            unsigned short* __restrict__ wt1, unsigned short* __restrict__ wt2,
                            const int* __restrict__ deg, float* __restrict__ dis,
                            const int* __restrict__ batch, int* __restrict__ start) {
  int b = blockIdx.x;
  if (b < 128) {                       // W transpose: 2*16384 elems
    int idx = b * 256 + threadIdx.x;
    int sel = idx >> 14;
    int r = idx & 16383;
    int k = r >> 7, n = r & 127;
    const float* W = sel ? W2 : W1;
    unsigned short* wt = sel ? wt2 : wt1;
    wt[n * HID + k] = f2bf(W[k * HID + n]);   // wt[n][k] = W[k][n]
  } else if (b < 324) {                // deg_inv_sqrt over 50000 nodes
    int i = (b - 128) * 256 + threadIdx.x;
    if (i < N_NODES) dis[i] = rsqrtf((float)deg[i] + 1.0f);  // +1 self-loop
  } else {                             // graph bounds (batch sorted)
    int t = threadIdx.x;
    if (t <= N_GRAPHS) {
      int lo = 0, hi = N_NODES;
      while (lo < hi) {
        int mid = (lo + hi) >> 1;
        if (batch[mid] < t) lo = mid + 1; else hi = mid;
      }
      start[t] = lo;
    }
  }
}

// ---------------- bf16 MFMA GEMM: T[n,:] = bf16( H[n,:] @ W ) ----------------
// 64 nodes/block, full 128 cols, K=128. 4 waves; wave w owns col-tiles {2w,2w+1}
// and all 4 node-tiles. 16x16x32 MFMA; A: m=lane&15,k=quad*8+j; B: n=lane&15,
// k=quad*8+j (from pre-transposed Wt); C/D: col=lane&15,row=quad*4+reg.
#define PAD 136   // +8 bf16 pad -> frag reads land 2-way (free) not 16-way
__global__ __launch_bounds__(256) void gemm_mfma_kernel(
    const float* __restrict__ H, const unsigned short* __restrict__ Wt,
    unsigned short* __restrict__ T, int n_nodes) {
  __shared__ unsigned short sA[64 * PAD];    // 17.4 KB (reused for output)
  __shared__ unsigned short sW[128 * PAD];   // 34.8 KB
  const int tid = threadIdx.x;
  const int lane = tid & 63;
  const int w = tid >> 6;
  const int l15 = lane & 15;
  const int quad = lane >> 4;
  const int base = blockIdx.x * 64;

  // stage Wt (coalesced us8): 128 rows x 16 chunks = 2048
#pragma unroll
  for (int i = 0; i < 8; ++i) {
    int idx = tid + i * 256;
    int row = idx >> 4;
    int col = (idx & 15) * 8;
    *(us8*)(sW + row * PAD + col) = *(const us8*)(Wt + row * HID + col);
  }
  // stage A: fp32 -> bf16: 64 rows x 32 float4 = 2048
#pragma unroll
  for (int i = 0; i < 8; ++i) {
    int idx = tid + i * 256;
    int nrow = idx >> 5;
    int c4 = (idx & 31) * 4;
    float4 v = make_float4(0.f, 0.f, 0.f, 0.f);
    int node = base + nrow;
    if (node < n_nodes) v = *(const float4*)(H + (size_t)node * HID + c4);
    us4 b;
    b.x = f2bf(v.x); b.y = f2bf(v.y); b.z = f2bf(v.z); b.w = f2bf(v.w);
    *(us4*)(sA + nrow * PAD + c4) = b;
  }
  __syncthreads();

  f32x4 acc[4][2];
#pragma unroll
  for (int nt = 0; nt < 4; ++nt)
#pragma unroll
    for (int c = 0; c < 2; ++c) acc[nt][c] = (f32x4)(0.f);

  const int ct0 = w * 2;
#pragma unroll
  for (int ks = 0; ks < 4; ++ks) {
    int koff = ks * 32 + quad * 8;
    bf16x8 a[4], bfr[2];
#pragma unroll
    for (int nt = 0; nt < 4; ++nt)
      a[nt] = *(const bf16x8*)(sA + (nt * 16 + l15) * PAD + koff);
#pragma unroll
    for (int c = 0; c < 2; ++c)
      bfr[c] = *(const bf16x8*)(sW + ((ct0 + c) * 16 + l15) * PAD + koff);
#pragma unroll
    for (int nt = 0; nt < 4; ++nt)
#pragma unroll
      for (int c = 0; c < 2; ++c)
        acc[nt][c] = __builtin_amdgcn_mfma_f32_16x16x32_bf16(a[nt], bfr[c], acc[nt][c], 0, 0, 0);
  }
  __syncthreads();

  // epilogue: acc -> bf16 in sA, then coalesced store (64 rows -> 4 iters)
#pragma unroll
  for (int nt = 0; nt < 4; ++nt)
#pragma unroll
    for (int c = 0; c < 2; ++c)
#pragma unroll
      for (int r = 0; r < 4; ++r)
        sA[(nt * 16 + quad * 4 + r) * PAD + (ct0 + c) * 16 + l15] = f2bf(acc[nt][c][r]);
  __syncthreads();
#pragma unroll
  for (int i = 0; i < 4; ++i) {
    int idx = tid + i * 256;
    int nrow = idx >> 4;
    int col = (idx & 15) * 8;
    int node = base + nrow;
    if (node < n_nodes)
      *(us8*)(T + (size_t)node * HID + col) = *(const us8*)(sA + nrow * PAD + col);
  }
}

// ---------------- normalized aggregation + bias + relu (bf16 ELL gather) ----
// one wave / dst node; lane owns 2 channels packed in one uint (2x bf16).
__global__ __launch_bounds__(256) void aggregate_kernel(
    const unsigned int* __restrict__ Tb, const unsigned short* __restrict__ ell,
    const int* __restrict__ deg, const float* __restrict__ dis,
    const float* __restrict__ bias, float* __restrict__ Hout) {
  int node = (blockIdx.x * blockDim.x + threadIdx.x) >> 6;
  int lane = threadIdx.x & 63;
  if (node >= N_NODES) return;
  float dd = dis[node];
  float2 b = ((const float2*)bias)[lane];
  unsigned sv = Tb[(size_t)node * 64 + lane];
  float wself = dd * dd;
  float ax = __int_as_float(sv << 16) * wself;
  float ay = __int_as_float(sv & 0xffff0000u) * wself;
  int m = min(deg[node], MAXDEG);
  int s0 = node << 6;
  int sidx = 0; float wv = 0.f;
  if (lane < m) {
    sidx = (int)ell[s0 + lane];       // coalesced (ELL row contiguous)
    wv = dis[sidx] * dd;              // parallel gather
  }
  int j = 0;
  for (; j + 8 <= m; j += 8) {
#pragma unroll
    for (int q = 0; q < 8; ++q) {     // 8 independent row gathers in flight
      int s = __builtin_amdgcn_readlane(sidx, j + q);
      float w = __int_as_float(__builtin_amdgcn_readlane(__float_as_int(wv), j + q));
      unsigned t = Tb[(size_t)s * 64 + lane];
      ax += w * __int_as_float(t << 16);
      ay += w * __int_as_float(t & 0xffff0000u);
    }
  }
  for (; j < m; ++j) {
    int s = __builtin_amdgcn_readlane(sidx, j);
    float w = __int_as_float(__builtin_amdgcn_readlane(__float_as_int(wv), j));
    unsigned t = Tb[(size_t)s * 64 + lane];
    ax += w * __int_as_float(t << 16);
    ay += w * __int_as_float(t & 0xffff0000u);
  }
  float2 o;
  o.x = fmaxf(ax + b.x, 0.f);
  o.y = fmaxf(ay + b.y, 0.f);
  ((float2*)Hout)[(size_t)node * 64 + lane] = o;
}

// ---------------- pooling: one block per graph ----------------
__global__ __launch_bounds__(256) void pool_kernel(
    const float* __restrict__ H, const int* __restrict__ start,
    float* __restrict__ pooled) {
  __shared__ float2 red[4][64];
  int g = blockIdx.x;
  int n0 = start[g], n1 = start[g + 1];
  int lane = threadIdx.x & 63, w = threadIdx.x >> 6;
  const float2* __restrict__ H2 = (const float2*)H;
  float ax = 0.f, ay = 0.f;
  for (int n = n0 + w; n < n1; n += 4) {
    float2 h = H2[(size_t)n * 64 + lane];
    ax += h.x; ay += h.y;
  }
  red[w][lane] = make_float2(ax, ay);
  __syncthreads();
  if (threadIdx.x < 64) {
    float2 a = red[0][lane], b1 = red[1][lane], c = red[2][lane], d = red[3][lane];
    float inv = 1.0f / fmaxf((float)(n1 - n0), 1.0f);
    float2 o;
    o.x = (a.x + b1.x + c.x + d.x) * inv;
    o.y = (a.y + b1.y + c.y + d.y) * inv;
    ((float2*)pooled)[g * 64 + lane] = o;
  }
}

// ---------------- FC head + log_softmax (1 wave / graph) ----------------
__global__ __launch_bounds__(64) void head_kernel(
    const float* __restrict__ pooled, const float* __restrict__ Wfc,
    const float* __restrict__ bfc, float* __restrict__ out) {
  int g = blockIdx.x;
  int lane = threadIdx.x;
  int o = lane & 15;
  float part = 0.f;
  for (int k = (lane >> 4); k < HID; k += 4)
    part += pooled[g * HID + k] * Wfc[k * OUT_C + o];
  part += __shfl_xor(part, 16);
  part += __shfl_xor(part, 32);
  float logit = part + bfc[o];
  float m = logit;
#pragma unroll
  for (int d = 8; d >= 1; d >>= 1) m = fmaxf(m, __shfl_xor(m, d, 16));
  float e = __expf(logit - m);
  float s = e;
#pragma unroll
  for (int d = 8; d >= 1; d >>= 1) s += __shfl_xor(s, d, 16);
  float r = logit - m - __logf(s);
  if (lane < 16) out[g * OUT_C + o] = r;
}

extern "C" void kernel_launch(void* const* d_in, const int* in_sizes, int n_in,
                              void* d_out, int out_size, void* d_ws, size_t ws_size,
                              hipStream_t stream) {
  const float* x    = (const float*)d_in[0];
  const int*   ei   = (const int*)d_in[1];
  const int*   batch= (const int*)d_in[2];
  const float* W1   = (const float*)d_in[3];
  const float* b1   = (const float*)d_in[4];
  const float* W2   = (const float*)d_in[5];
  const float* b2   = (const float*)d_in[6];
  const float* Wfc  = (const float*)d_in[7];
  const float* bfc  = (const float*)d_in[8];
  float* out = (float*)d_out;
  const int* src = ei;              // edge_index[0]
  const int* dst = ei + N_EDGES;    // edge_index[1]

  char* p = (char*)d_ws;
  auto alloc = [&](size_t bytes) { char* r = p; p += (bytes + 255) & ~255ull; return r; };
  int*   degI   = (int*)alloc((size_t)N_NODES * 4);
  float* dis    = (float*)alloc((size_t)N_NODES * 4);
  int*   start  = (int*)alloc((N_GRAPHS + 1) * 4);
  float* pooled = (float*)alloc((size_t)N_GRAPHS * HID * 4);
  unsigned short* dst16 = (unsigned short*)alloc((size_t)N_EDGES * 2);       // 1.6 MB
  unsigned short* ell = (unsigned short*)alloc((size_t)N_NODES * MAXDEG * 2); // 6.4 MB
  unsigned short* wt1 = (unsigned short*)alloc((size_t)HID * HID * 2);
  unsigned short* wt2 = (unsigned short*)alloc((size_t)HID * HID * 2);
  unsigned short* T   = (unsigned short*)alloc((size_t)N_NODES * HID * 2);
  float* H      = (float*)alloc((size_t)N_NODES * HID * 4);

  compact_kernel<<<(N_EDGES / 4 + 255) / 256, 256, 0, stream>>>(dst, dst16);
  fill_win_kernel<<<N_NODES / WIN, 256, 0, stream>>>(src, dst16, degI, ell);
  prep_kernel<<<325, 256, 0, stream>>>(W1, W2, wt1, wt2, degI, dis, batch, start);

  int gemm_blocks = (N_NODES + 63) / 64;
  int agg_blocks  = (N_NODES * 64 + 255) / 256;

  gemm_mfma_kernel<<<gemm_blocks, 256, 0, stream>>>(x, wt1, T, N_NODES);
  aggregate_kernel<<<agg_blocks, 256, 0, stream>>>((const unsigned int*)T, ell, degI, dis, b1, H);
  gemm_mfma_kernel<<<gemm_blocks, 256, 0, stream>>>(H, wt2, T, N_NODES);
  aggregate_kernel<<<agg_blocks, 256, 0, stream>>>((const unsigned int*)T, ell, degI, dis, b2, H);

  pool_kernel<<<N_GRAPHS, 256, 0, stream>>>(H, start, pooled);
  head_kernel<<<N_GRAPHS, 64, 0, stream>>>(pooled, Wfc, bfc, out);
}

// Round 8
// 272.072 us; speedup vs baseline: 1.8090x; 1.8090x over previous
//
#include <hip/hip_runtime.h>

#define N_NODES  50000
#define N_EDGES  800000
#define HID      128
#define OUT_C    16
#define N_GRAPHS 128
#define MAXDEG   64     // Poisson(16): P(deg>=64) ~ 1e-19/node — clamped anyway
#define NSLICE   6250   // N_NODES / 8; slice s owns [s*6250,(s+1)*6250)
#define EPB      8192   // edges per fill chunk
#define FILLB    784    // 98 chunks x 8 slices
#define GEMMB    782    // ceil(50000/64)
#define PAD      136    // +8 bf16 pad -> frag reads 2-way (free) not 16-way

typedef __attribute__((ext_vector_type(8))) short bf16x8;
typedef __attribute__((ext_vector_type(4))) float f32x4;
typedef __attribute__((ext_vector_type(8))) unsigned short us8;
typedef __attribute__((ext_vector_type(4))) unsigned short us4;

__device__ __forceinline__ unsigned short f2bf(float f) {
  unsigned u = __float_as_uint(f);
  u += 0x7fffu + ((u >> 16) & 1u);   // RNE
  return (unsigned short)(u >> 16);
}

// ---------------- XCD-sharded degree-count + ELL fill (round-6, 55us) -------
__device__ __forceinline__ void fill_body(
    int b, const int* __restrict__ src, const int* __restrict__ dst,
    int* __restrict__ deg, unsigned short* __restrict__ ell) {
  const int slice = b & 7;
  const int e0 = (b >> 3) * EPB;
  const int e1 = min(e0 + EPB, N_EDGES);
  const unsigned lo = slice * NSLICE;
  for (int e = e0 + threadIdx.x; e < e1; e += 256) {
    int d = dst[e];
    if ((unsigned)(d - lo) < (unsigned)NSLICE) {
      int p = atomicAdd(&deg[d], 1);
      if (p < MAXDEG) ell[(d << 6) + p] = (unsigned short)src[e];
    }
  }
}

// ---------------- bf16 MFMA GEMM body: T[n,:] = bf16( H[n,:] @ W ) ----------
// 64 nodes/block, K=128, full 128 cols. W is raw fp32 [k][n]: staged with
// on-the-fly transpose+bf16 (LDS write conflicts negligible: once per block).
// 16x16x32 MFMA; A: m=lane&15,k=quad*8+j; B: n=lane&15,k=quad*8+j;
// C/D: col=lane&15,row=quad*4+reg.
__device__ __forceinline__ void gemm_body(
    int blk, const float* __restrict__ H, const float* __restrict__ W,
    unsigned short* __restrict__ T, int n_nodes, unsigned short* smem) {
  unsigned short* sA = smem;             // 64 x PAD (reused for output)
  unsigned short* sW = smem + 64 * PAD;  // 128 x PAD, [n][k]
  const int tid = threadIdx.x;
  const int lane = tid & 63;
  const int w = tid >> 6;
  const int l15 = lane & 15;
  const int quad = lane >> 4;
  const int base = blk * 64;

  // stage W transposed: 128x128 fp32 = 4096 float4; sW[n][k] = bf16(W[k][n])
#pragma unroll
  for (int i = 0; i < 16; ++i) {
    int idx = tid + i * 256;
    int k = idx >> 5;
    int n0 = (idx & 31) << 2;
    float4 v = *(const float4*)(W + (size_t)k * HID + n0);
    sW[(n0 + 0) * PAD + k] = f2bf(v.x);
    sW[(n0 + 1) * PAD + k] = f2bf(v.y);
    sW[(n0 + 2) * PAD + k] = f2bf(v.z);
    sW[(n0 + 3) * PAD + k] = f2bf(v.w);
  }
  // stage A: fp32 -> bf16: 64 rows x 32 float4 = 2048
#pragma unroll
  for (int i = 0; i < 8; ++i) {
    int idx = tid + i * 256;
    int nrow = idx >> 5;
    int c4 = (idx & 31) * 4;
    float4 v = make_float4(0.f, 0.f, 0.f, 0.f);
    int node = base + nrow;
    if (node < n_nodes) v = *(const float4*)(H + (size_t)node * HID + c4);
    us4 b;
    b.x = f2bf(v.x); b.y = f2bf(v.y); b.z = f2bf(v.z); b.w = f2bf(v.w);
    *(us4*)(sA + nrow * PAD + c4) = b;
  }
  __syncthreads();

  f32x4 acc[4][2];
#pragma unroll
  for (int nt = 0; nt < 4; ++nt)
#pragma unroll
    for (int c = 0; c < 2; ++c) acc[nt][c] = (f32x4)(0.f);

  const int ct0 = w * 2;
#pragma unroll
  for (int ks = 0; ks < 4; ++ks) {
    int koff = ks * 32 + quad * 8;
    bf16x8 a[4], bfr[2];
#pragma unroll
    for (int nt = 0; nt < 4; ++nt)
      a[nt] = *(const bf16x8*)(sA + (nt * 16 + l15) * PAD + koff);
#pragma unroll
    for (int c = 0; c < 2; ++c)
      bfr[c] = *(const bf16x8*)(sW + ((ct0 + c) * 16 + l15) * PAD + koff);
#pragma unroll
    for (int nt = 0; nt < 4; ++nt)
#pragma unroll
      for (int c = 0; c < 2; ++c)
        acc[nt][c] = __builtin_amdgcn_mfma_f32_16x16x32_bf16(a[nt], bfr[c], acc[nt][c], 0, 0, 0);
  }
  __syncthreads();

  // epilogue: acc -> bf16 in sA, then coalesced store (64 rows -> 4 iters)
#pragma unroll
  for (int nt = 0; nt < 4; ++nt)
#pragma unroll
    for (int c = 0; c < 2; ++c)
#pragma unroll
      for (int r = 0; r < 4; ++r)
        sA[(nt * 16 + quad * 4 + r) * PAD + (ct0 + c) * 16 + l15] = f2bf(acc[nt][c][r]);
  __syncthreads();
#pragma unroll
  for (int i = 0; i < 4; ++i) {
    int idx = tid + i * 256;
    int nrow = idx >> 4;
    int col = (idx & 15) * 8;
    int node = base + nrow;
    if (node < n_nodes)
      *(us8*)(T + (size_t)node * HID + col) = *(const us8*)(sA + nrow * PAD + col);
  }
}

// ---------------- mega1: fill (0..783) | bounds (784) | gemm1 (785..1566) ----
// fill/gemm1/bounds are mutually independent; grid-fusing hides gemm1+bounds
// entirely under fill's 55us (same-stream kernels would serialize).
__global__ __launch_bounds__(256) void mega1_kernel(
    const int* __restrict__ src, const int* __restrict__ dst,
    int* __restrict__ deg, unsigned short* __restrict__ ell,
    const int* __restrict__ batch, int* __restrict__ start,
    const float* __restrict__ x, const float* __restrict__ W1,
    unsigned short* __restrict__ T) {
  __shared__ unsigned short smem[192 * PAD];   // 52 KB (gemm branch only)
  int b = blockIdx.x;
  if (b < FILLB) {
    fill_body(b, src, dst, deg, ell);
  } else if (b == FILLB) {
    int t = threadIdx.x;                       // graph bounds (batch sorted)
    if (t <= N_GRAPHS) {
      int lo = 0, hi = N_NODES;
      while (lo < hi) {
        int mid = (lo + hi) >> 1;
        if (batch[mid] < t) lo = mid + 1; else hi = mid;
      }
      start[t] = lo;
    }
  } else {
    gemm_body(b - FILLB - 1, x, W1, T, N_NODES, smem);
  }
}

// ---------------- standalone gemm (layer 2) ----------------
__global__ __launch_bounds__(256) void gemm_kernel(
    const float* __restrict__ H, const float* __restrict__ W,
    unsigned short* __restrict__ T) {
  __shared__ unsigned short smem[192 * PAD];
  gemm_body(blockIdx.x, H, W, T, N_NODES, smem);
}

// ---------------- normalized aggregation + bias + relu (bf16 ELL gather) ----
// one wave / dst node; lane owns 2 channels packed in one uint (2x bf16).
// deg_inv_sqrt computed on the fly from deg (kills the dis array+pass).
__global__ __launch_bounds__(256) void aggregate_kernel(
    const unsigned int* __restrict__ Tb, const unsigned short* __restrict__ ell,
    const int* __restrict__ deg, const float* __restrict__ bias,
    float* __restrict__ Hout) {
  int node = (blockIdx.x * blockDim.x + threadIdx.x) >> 6;
  int lane = threadIdx.x & 63;
  if (node >= N_NODES) return;
  int dn = deg[node];
  float dd = rsqrtf((float)dn + 1.0f);
  float2 b = ((const float2*)bias)[lane];
  unsigned sv = Tb[(size_t)node * 64 + lane];
  float wself = dd * dd;
  float ax = __int_as_float(sv << 16) * wself;
  float ay = __int_as_float(sv & 0xffff0000u) * wself;
  int m = min(dn, MAXDEG);
  int s0 = node << 6;
  int sidx = 0; float wv = 0.f;
  if (lane < m) {
    sidx = (int)ell[s0 + lane];       // coalesced (ELL row contiguous)
    wv = rsqrtf((float)deg[sidx] + 1.0f) * dd;   // parallel gather
  }
  int j = 0;
  for (; j + 8 <= m; j += 8) {
#pragma unroll
    for (int q = 0; q < 8; ++q) {     // 8 independent row gathers in flight
      int s = __builtin_amdgcn_readlane(sidx, j + q);
      float w = __int_as_float(__builtin_amdgcn_readlane(__float_as_int(wv), j + q));
      unsigned t = Tb[(size_t)s * 64 + lane];
      ax += w * __int_as_float(t << 16);
      ay += w * __int_as_float(t & 0xffff0000u);
    }
  }
  for (; j < m; ++j) {
    int s = __builtin_amdgcn_readlane(sidx, j);
    float w = __int_as_float(__builtin_amdgcn_readlane(__float_as_int(wv), j));
    unsigned t = Tb[(size_t)s * 64 + lane];
    ax += w * __int_as_float(t << 16);
    ay += w * __int_as_float(t & 0xffff0000u);
  }
  float2 o;
  o.x = fmaxf(ax + b.x, 0.f);
  o.y = fmaxf(ay + b.y, 0.f);
  ((float2*)Hout)[(size_t)node * 64 + lane] = o;
}

// ---------------- fused pool + FC head + log_softmax: 1 block / graph -------
__global__ __launch_bounds__(256) void pool_head_kernel(
    const float* __restrict__ H, const int* __restrict__ start,
    const float* __restrict__ Wfc, const float* __restrict__ bfc,
    float* __restrict__ out) {
  __shared__ float2 red[4][64];
  __shared__ float spool[HID];
  int g = blockIdx.x;
  int n0 = start[g], n1 = start[g + 1];
  int lane = threadIdx.x & 63, w = threadIdx.x >> 6;
  const float2* __restrict__ H2 = (const float2*)H;
  float ax = 0.f, ay = 0.f;
  for (int n = n0 + w; n < n1; n += 4) {
    float2 h = H2[(size_t)n * 64 + lane];
    ax += h.x; ay += h.y;
  }
  red[w][lane] = make_float2(ax, ay);
  __syncthreads();
  if (threadIdx.x < 64) {
    float2 a = red[0][lane], b1 = red[1][lane], c = red[2][lane], d = red[3][lane];
    float inv = 1.0f / fmaxf((float)(n1 - n0), 1.0f);
    spool[lane * 2]     = (a.x + b1.x + c.x + d.x) * inv;
    spool[lane * 2 + 1] = (a.y + b1.y + c.y + d.y) * inv;
  }
  __syncthreads();
  if (threadIdx.x < 64) {
    int o = lane & 15;
    float part = 0.f;
    for (int k = (lane >> 4); k < HID; k += 4)
      part += spool[k] * Wfc[k * OUT_C + o];
    part += __shfl_xor(part, 16);
    part += __shfl_xor(part, 32);
    float logit = part + bfc[o];
    float m = logit;
#pragma unroll
    for (int d = 8; d >= 1; d >>= 1) m = fmaxf(m, __shfl_xor(m, d, 16));
    float e = __expf(logit - m);
    float s = e;
#pragma unroll
    for (int d = 8; d >= 1; d >>= 1) s += __shfl_xor(s, d, 16);
    float r = logit - m - __logf(s);
    if (lane < 16) out[g * OUT_C + o] = r;
  }
}

extern "C" void kernel_launch(void* const* d_in, const int* in_sizes, int n_in,
                              void* d_out, int out_size, void* d_ws, size_t ws_size,
                              hipStream_t stream) {
  const float* x    = (const float*)d_in[0];
  const int*   ei   = (const int*)d_in[1];
  const int*   batch= (const int*)d_in[2];
  const float* W1   = (const float*)d_in[3];
  const float* b1   = (const float*)d_in[4];
  const float* W2   = (const float*)d_in[5];
  const float* b2   = (const float*)d_in[6];
  const float* Wfc  = (const float*)d_in[7];
  const float* bfc  = (const float*)d_in[8];
  float* out = (float*)d_out;
  const int* src = ei;              // edge_index[0]
  const int* dst = ei + N_EDGES;    // edge_index[1]

  char* p = (char*)d_ws;
  auto alloc = [&](size_t bytes) { char* r = p; p += (bytes + 255) & ~255ull; return r; };
  int*   degI   = (int*)alloc((size_t)N_NODES * 4);
  int*   start  = (int*)alloc((N_GRAPHS + 1) * 4);
  unsigned short* ell = (unsigned short*)alloc((size_t)N_NODES * MAXDEG * 2); // 6.4 MB
  unsigned short* T   = (unsigned short*)alloc((size_t)N_NODES * HID * 2);
  float* H      = (float*)alloc((size_t)N_NODES * HID * 4);

  hipMemsetAsync(degI, 0, (size_t)N_NODES * 4, stream);

  int agg_blocks = (N_NODES * 64 + 255) / 256;

  mega1_kernel<<<FILLB + 1 + GEMMB, 256, 0, stream>>>(src, dst, degI, ell,
                                                      batch, start, x, W1, T);
  aggregate_kernel<<<agg_blocks, 256, 0, stream>>>((const unsigned int*)T, ell, degI, b1, H);
  gemm_kernel<<<GEMMB, 256, 0, stream>>>(H, W2, T);
  aggregate_kernel<<<agg_blocks, 256, 0, stream>>>((const unsigned int*)T, ell, degI, b2, H);
  pool_head_kernel<<<N_GRAPHS, 256, 0, stream>>>(H, start, Wfc, bfc, out);
}

// Round 9
// 266.842 us; speedup vs baseline: 1.8444x; 1.0196x over previous
//
#include <hip/hip_runtime.h>

#define N_NODES  50000
#define N_EDGES  800000
#define HID      128
#define OUT_C    16
#define N_GRAPHS 128
#define MAXDEG   64     // Poisson(16): P(deg>=64) ~ 1e-19/node — clamped anyway
#define NSLICE   6250   // N_NODES / 8; slice s owns [s*6250,(s+1)*6250)
#define EPB      8192   // edges per fill chunk
#define FILLB    784    // 98 chunks x 8 slices
#define PREPB    128    // W-transpose blocks
#define GEMMB    782    // ceil(50000/64)
#define PAD      136    // +8 bf16 pad -> frag reads 2-way (free) not 16-way

typedef __attribute__((ext_vector_type(8))) short bf16x8;
typedef __attribute__((ext_vector_type(4))) float f32x4;
typedef __attribute__((ext_vector_type(8))) unsigned short us8;
typedef __attribute__((ext_vector_type(4))) unsigned short us4;

__device__ __forceinline__ unsigned short f2bf(float f) {
  unsigned u = __float_as_uint(f);
  u += 0x7fffu + ((u >> 16) & 1u);   // RNE
  return (unsigned short)(u >> 16);
}

// ---------------- mega0: fill (0..783) | bounds (784) | W-prep (785..912) ----
// All branches LDS-free (round-8 lesson: static smem in a branchy mega kernel
// caps EVERY block's occupancy — fill lost its latency hiding). Fill is
// atomic-chain-bound (~800k global atomics ≈ 55us across rounds 4/5/6
// regardless of memory pattern), so prep/bounds hide under it for free.
__global__ __launch_bounds__(256) void mega0_kernel(
    const int* __restrict__ src, const int* __restrict__ dst,
    int* __restrict__ deg, unsigned short* __restrict__ ell,
    const int* __restrict__ batch, int* __restrict__ start,
    const float* __restrict__ W1, const float* __restrict__ W2,
    unsigned short* __restrict__ wt1, unsigned short* __restrict__ wt2) {
  int b = blockIdx.x;
  if (b < FILLB) {
    // XCD-sharded degree-count + ELL fill (blockIdx%8 -> XCD round-robin).
    // NT-load the 8x-replicated dst stream so it doesn't churn dirty ELL
    // lines out of L2.
    const int slice = b & 7;
    const int e0 = (b >> 3) * EPB;
    const int e1 = min(e0 + EPB, N_EDGES);
    const unsigned lo = slice * NSLICE;
    for (int e = e0 + threadIdx.x; e < e1; e += 256) {
      int d = __builtin_nontemporal_load(dst + e);
      if ((unsigned)(d - lo) < (unsigned)NSLICE) {
        int p = atomicAdd(&deg[d], 1);
        if (p < MAXDEG) ell[(d << 6) + p] = (unsigned short)src[e];
      }
    }
  } else if (b == FILLB) {
    int t = threadIdx.x;                       // graph bounds (batch sorted)
    if (t <= N_GRAPHS) {
      int lo = 0, hi = N_NODES;
      while (lo < hi) {
        int mid = (lo + hi) >> 1;
        if (batch[mid] < t) lo = mid + 1; else hi = mid;
      }
      start[t] = lo;
    }
  } else {
    int idx = (b - FILLB - 1) * 256 + threadIdx.x;   // 0..32767
    int sel = idx >> 14;
    int r = idx & 16383;
    int k = r >> 7, n = r & 127;
    const float* W = sel ? W2 : W1;
    unsigned short* wt = sel ? wt2 : wt1;
    wt[n * HID + k] = f2bf(W[k * HID + n]);   // wt[n][k] = W[k][n]
  }
}

// ---------------- shared MFMA compute+store (after staging, pre-sync'd) -----
// 16x16x32 MFMA; A: m=lane&15,k=quad*8+j; B: n=lane&15,k=quad*8+j (from
// pre-transposed Wt, zero bank conflicts); C/D: col=lane&15,row=quad*4+reg.
__device__ __forceinline__ void gemm_compute_store(
    unsigned short* sA, unsigned short* sW, unsigned short* __restrict__ T,
    int base) {
  const int tid = threadIdx.x;
  const int lane = tid & 63;
  const int w = tid >> 6;
  const int l15 = lane & 15;
  const int quad = lane >> 4;
  __syncthreads();

  f32x4 acc[4][2];
#pragma unroll
  for (int nt = 0; nt < 4; ++nt)
#pragma unroll
    for (int c = 0; c < 2; ++c) acc[nt][c] = (f32x4)(0.f);

  const int ct0 = w * 2;
#pragma unroll
  for (int ks = 0; ks < 4; ++ks) {
    int koff = ks * 32 + quad * 8;
    bf16x8 a[4], bfr[2];
#pragma unroll
    for (int nt = 0; nt < 4; ++nt)
      a[nt] = *(const bf16x8*)(sA + (nt * 16 + l15) * PAD + koff);
#pragma unroll
    for (int c = 0; c < 2; ++c)
      bfr[c] = *(const bf16x8*)(sW + ((ct0 + c) * 16 + l15) * PAD + koff);
#pragma unroll
    for (int nt = 0; nt < 4; ++nt)
#pragma unroll
      for (int c = 0; c < 2; ++c)
        acc[nt][c] = __builtin_amdgcn_mfma_f32_16x16x32_bf16(a[nt], bfr[c], acc[nt][c], 0, 0, 0);
  }
  __syncthreads();

  // epilogue: acc -> bf16 in sA, then coalesced store (64 rows -> 4 iters)
#pragma unroll
  for (int nt = 0; nt < 4; ++nt)
#pragma unroll
    for (int c = 0; c < 2; ++c)
#pragma unroll
      for (int r = 0; r < 4; ++r)
        sA[(nt * 16 + quad * 4 + r) * PAD + (ct0 + c) * 16 + l15] = f2bf(acc[nt][c][r]);
  __syncthreads();
#pragma unroll
  for (int i = 0; i < 4; ++i) {
    int idx = tid + i * 256;
    int nrow = idx >> 4;
    int col = (idx & 15) * 8;
    int node = base + nrow;
    if (node < N_NODES)
      *(us8*)(T + (size_t)node * HID + col) = *(const us8*)(sA + nrow * PAD + col);
  }
}

__device__ __forceinline__ void stage_w(unsigned short* sW,
                                        const unsigned short* __restrict__ Wt) {
#pragma unroll
  for (int i = 0; i < 8; ++i) {        // 128 rows x 16 us8 chunks = 2048
    int idx = threadIdx.x + i * 256;
    int row = idx >> 4;
    int col = (idx & 15) * 8;
    *(us8*)(sW + row * PAD + col) = *(const us8*)(Wt + row * HID + col);
  }
}

// gemm layer 1: A from fp32 x (convert to bf16 during staging)
__global__ __launch_bounds__(256) void gemm_f32_kernel(
    const float* __restrict__ H, const unsigned short* __restrict__ Wt,
    unsigned short* __restrict__ T) {
  __shared__ unsigned short smem[192 * PAD];   // 52 KB
  unsigned short* sA = smem;
  unsigned short* sW = smem + 64 * PAD;
  stage_w(sW, Wt);
  const int base = blockIdx.x * 64;
#pragma unroll
  for (int i = 0; i < 8; ++i) {        // 64 rows x 32 float4 = 2048
    int idx = threadIdx.x + i * 256;
    int nrow = idx >> 5;
    int c4 = (idx & 31) * 4;
    float4 v = make_float4(0.f, 0.f, 0.f, 0.f);
    int node = base + nrow;
    if (node < N_NODES) v = *(const float4*)(H + (size_t)node * HID + c4);
    us4 b;
    b.x = f2bf(v.x); b.y = f2bf(v.y); b.z = f2bf(v.z); b.w = f2bf(v.w);
    *(us4*)(sA + nrow * PAD + c4) = b;
  }
  gemm_compute_store(sA, sW, T, base);
}

// gemm layer 2: A from bf16 H (straight us8 copy)
__global__ __launch_bounds__(256) void gemm_bf16_kernel(
    const unsigned short* __restrict__ Hb, const unsigned short* __restrict__ Wt,
    unsigned short* __restrict__ T) {
  __shared__ unsigned short smem[192 * PAD];   // 52 KB
  unsigned short* sA = smem;
  unsigned short* sW = smem + 64 * PAD;
  stage_w(sW, Wt);
  const int base = blockIdx.x * 64;
#pragma unroll
  for (int i = 0; i < 4; ++i) {        // 64 rows x 16 us8 chunks = 1024
    int idx = threadIdx.x + i * 256;
    int nrow = idx >> 4;
    int col = (idx & 15) * 8;
    us8 v = (us8)(0);
    int node = base + nrow;
    if (node < N_NODES) v = *(const us8*)(Hb + (size_t)node * HID + col);
    *(us8*)(sA + nrow * PAD + col) = v;
  }
  gemm_compute_store(sA, sW, T, base);
}

// ---------------- normalized aggregation + bias + relu (bf16 ELL gather) ----
// one wave / dst node; lane owns 2 channels packed in one uint (2x bf16).
// deg_inv_sqrt computed on the fly from deg. Output H stored bf16-packed
// (gemm2 rounds to bf16 anyway — identical precision path, 1/2 the bytes).
__global__ __launch_bounds__(256) void aggregate_kernel(
    const unsigned int* __restrict__ Tb, const unsigned short* __restrict__ ell,
    const int* __restrict__ deg, const float* __restrict__ bias,
    unsigned int* __restrict__ Hb) {
  int node = (blockIdx.x * blockDim.x + threadIdx.x) >> 6;
  int lane = threadIdx.x & 63;
  if (node >= N_NODES) return;
  int dn = deg[node];
  float dd = rsqrtf((float)dn + 1.0f);
  float2 b = ((const float2*)bias)[lane];
  unsigned sv = Tb[(size_t)node * 64 + lane];
  float wself = dd * dd;
  float ax = __int_as_float(sv << 16) * wself;
  float ay = __int_as_float(sv & 0xffff0000u) * wself;
  int m = min(dn, MAXDEG);
  int s0 = node << 6;
  int sidx = 0; float wv = 0.f;
  if (lane < m) {
    sidx = (int)ell[s0 + lane];       // coalesced (ELL row contiguous)
    wv = rsqrtf((float)deg[sidx] + 1.0f) * dd;   // parallel gather
  }
  int j = 0;
  for (; j + 8 <= m; j += 8) {
#pragma unroll
    for (int q = 0; q < 8; ++q) {     // 8 independent row gathers in flight
      int s = __builtin_amdgcn_readlane(sidx, j + q);
      float w = __int_as_float(__builtin_amdgcn_readlane(__float_as_int(wv), j + q));
      unsigned t = Tb[(size_t)s * 64 + lane];
      ax += w * __int_as_float(t << 16);
      ay += w * __int_as_float(t & 0xffff0000u);
    }
  }
  for (; j < m; ++j) {
    int s = __builtin_amdgcn_readlane(sidx, j);
    float w = __int_as_float(__builtin_amdgcn_readlane(__float_as_int(wv), j));
    unsigned t = Tb[(size_t)s * 64 + lane];
    ax += w * __int_as_float(t << 16);
    ay += w * __int_as_float(t & 0xffff0000u);
  }
  float ox = fmaxf(ax + b.x, 0.f);
  float oy = fmaxf(ay + b.y, 0.f);
  Hb[(size_t)node * 64 + lane] =
      (unsigned)f2bf(ox) | ((unsigned)f2bf(oy) << 16);
}

// ---------------- fused pool + FC head + log_softmax: 1 block / graph -------
__global__ __launch_bounds__(256) void pool_head_kernel(
    const unsigned int* __restrict__ Hb, const int* __restrict__ start,
    const float* __restrict__ Wfc, const float* __restrict__ bfc,
    float* __restrict__ out) {
  __shared__ float2 red[4][64];
  __shared__ float spool[HID];
  int g = blockIdx.x;
  int n0 = start[g], n1 = start[g + 1];
  int lane = threadIdx.x & 63, w = threadIdx.x >> 6;
  float ax = 0.f, ay = 0.f;
  for (int n = n0 + w; n < n1; n += 4) {
    unsigned h = Hb[(size_t)n * 64 + lane];
    ax += __int_as_float(h << 16);
    ay += __int_as_float(h & 0xffff0000u);
  }
  red[w][lane] = make_float2(ax, ay);
  __syncthreads();
  if (threadIdx.x < 64) {
    float2 a = red[0][lane], b1 = red[1][lane], c = red[2][lane], d = red[3][lane];
    float inv = 1.0f / fmaxf((float)(n1 - n0), 1.0f);
    spool[lane * 2]     = (a.x + b1.x + c.x + d.x) * inv;
    spool[lane * 2 + 1] = (a.y + b1.y + c.y + d.y) * inv;
  }
  __syncthreads();
  if (threadIdx.x < 64) {
    int o = lane & 15;
    float part = 0.f;
    for (int k = (lane >> 4); k < HID; k += 4)
      part += spool[k] * Wfc[k * OUT_C + o];
    part += __shfl_xor(part, 16);
    part += __shfl_xor(part, 32);
    float logit = part + bfc[o];
    float m = logit;
#pragma unroll
    for (int d = 8; d >= 1; d >>= 1) m = fmaxf(m, __shfl_xor(m, d, 16));
    float e = __expf(logit - m);
    float s = e;
#pragma unroll
    for (int d = 8; d >= 1; d >>= 1) s += __shfl_xor(s, d, 16);
    float r = logit - m - __logf(s);
    if (lane < 16) out[g * OUT_C + o] = r;
  }
}

extern "C" void kernel_launch(void* const* d_in, const int* in_sizes, int n_in,
                              void* d_out, int out_size, void* d_ws, size_t ws_size,
                              hipStream_t stream) {
  const float* x    = (const float*)d_in[0];
  const int*   ei   = (const int*)d_in[1];
  const int*   batch= (const int*)d_in[2];
  const float* W1   = (const float*)d_in[3];
  const float* b1   = (const float*)d_in[4];
  const float* W2   = (const float*)d_in[5];
  const float* b2   = (const float*)d_in[6];
  const float* Wfc  = (const float*)d_in[7];
  const float* bfc  = (const float*)d_in[8];
  float* out = (float*)d_out;
  const int* src = ei;              // edge_index[0]
  const int* dst = ei + N_EDGES;    // edge_index[1]

  char* p = (char*)d_ws;
  auto alloc = [&](size_t bytes) { char* r = p; p += (bytes + 255) & ~255ull; return r; };
  int*   degI   = (int*)alloc((size_t)N_NODES * 4);
  int*   start  = (int*)alloc((N_GRAPHS + 1) * 4);
  unsigned short* ell = (unsigned short*)alloc((size_t)N_NODES * MAXDEG * 2); // 6.4 MB
  unsigned short* wt1 = (unsigned short*)alloc((size_t)HID * HID * 2);
  unsigned short* wt2 = (unsigned short*)alloc((size_t)HID * HID * 2);
  unsigned short* T   = (unsigned short*)alloc((size_t)N_NODES * HID * 2);   // 12.8 MB
  unsigned short* Hb  = (unsigned short*)alloc((size_t)N_NODES * HID * 2);   // 12.8 MB

  hipMemsetAsync(degI, 0, (size_t)N_NODES * 4, stream);

  int agg_blocks = (N_NODES * 64 + 255) / 256;

  mega0_kernel<<<FILLB + 1 + PREPB, 256, 0, stream>>>(src, dst, degI, ell,
                                                      batch, start, W1, W2, wt1, wt2);
  gemm_f32_kernel<<<GEMMB, 256, 0, stream>>>(x, wt1, T);
  aggregate_kernel<<<agg_blocks, 256, 0, stream>>>((const unsigned int*)T, ell, degI, b1,
                                                   (unsigned int*)Hb);
  gemm_bf16_kernel<<<GEMMB, 256, 0, stream>>>(Hb, wt2, T);
  aggregate_kernel<<<agg_blocks, 256, 0, stream>>>((const unsigned int*)T, ell, degI, b2,
                                                   (unsigned int*)Hb);
  pool_head_kernel<<<N_GRAPHS, 256, 0, stream>>>((const unsigned int*)Hb, start,
                                                 Wfc, bfc, out);
}

// Round 10
// 255.540 us; speedup vs baseline: 1.9260x; 1.0442x over previous
//
#include <hip/hip_runtime.h>

#define N_NODES  50000
#define N_EDGES  800000
#define HID      128
#define OUT_C    16
#define N_GRAPHS 128
#define MAXDEG   64     // Poisson(16): P(deg>=64) ~ 1e-19/node — clamped anyway
#define NSLICE   6250   // N_NODES / 8; slice s owns [s*6250,(s+1)*6250)
#define EPB      8192   // edges per fill chunk
#define FILLB    784    // 98 chunks x 8 slices
#define GEMMB    782    // ceil(50000/64)
#define PAD      136    // +8 bf16 pad -> frag reads 2-way (free) not 16-way

typedef __attribute__((ext_vector_type(8))) short bf16x8;
typedef __attribute__((ext_vector_type(4))) float f32x4;
typedef __attribute__((ext_vector_type(8))) unsigned short us8;
typedef __attribute__((ext_vector_type(4))) unsigned short us4;

__device__ __forceinline__ unsigned short f2bf(float f) {
  unsigned u = __float_as_uint(f);
  u += 0x7fffu + ((u >> 16) & 1u);   // RNE
  return (unsigned short)(u >> 16);
}

// ---------------- shared MFMA compute+store (B direct from fp32 W) ----------
// 16x16x32 MFMA; A: m=lane&15,k=quad*8+j (LDS, PAD keeps reads 2-way);
// B: n=lane&15,k=quad*8+j — loaded STRAIGHT from global W[k][n]: per quad the
// 16 lanes read 16 consecutive floats (one 64-B line), identical across all
// blocks -> L2 broadcast. No LDS for W at all (round-8 lesson: in-LDS
// transpose = 6.4M bank conflicts; round-9 wt prep = extra pass). LDS is just
// sA = 17.4 KB -> fused fill blocks keep their occupancy.
// C/D: col=lane&15,row=quad*4+reg.
__device__ __forceinline__ void gemm_compute_store(
    unsigned short* sA, const float* __restrict__ W,
    unsigned short* __restrict__ T, int base) {
  const int tid = threadIdx.x;
  const int lane = tid & 63;
  const int w = tid >> 6;
  const int l15 = lane & 15;
  const int quad = lane >> 4;
  __syncthreads();

  f32x4 acc[4][2];
#pragma unroll
  for (int nt = 0; nt < 4; ++nt)
#pragma unroll
    for (int c = 0; c < 2; ++c) acc[nt][c] = (f32x4)(0.f);

  const int ct0 = w * 2;
  const int ncol = ct0 * 16 + l15;
#pragma unroll
  for (int ks = 0; ks < 4; ++ks) {
    const int koff = ks * 32 + quad * 8;
    bf16x8 a[4], bfr[2];
#pragma unroll
    for (int c = 0; c < 2; ++c) {
      const float* wp = W + (size_t)koff * HID + ncol + c * 16;
#pragma unroll
      for (int j = 0; j < 8; ++j) bfr[c][j] = (short)f2bf(wp[(size_t)j * HID]);
    }
#pragma unroll
    for (int nt = 0; nt < 4; ++nt)
      a[nt] = *(const bf16x8*)(sA + (nt * 16 + l15) * PAD + koff);
#pragma unroll
    for (int nt = 0; nt < 4; ++nt)
#pragma unroll
      for (int c = 0; c < 2; ++c)
        acc[nt][c] = __builtin_amdgcn_mfma_f32_16x16x32_bf16(a[nt], bfr[c], acc[nt][c], 0, 0, 0);
  }
  __syncthreads();

  // epilogue: acc -> bf16 in sA, then coalesced store (64 rows -> 4 iters)
#pragma unroll
  for (int nt = 0; nt < 4; ++nt)
#pragma unroll
    for (int c = 0; c < 2; ++c)
#pragma unroll
      for (int r = 0; r < 4; ++r)
        sA[(nt * 16 + quad * 4 + r) * PAD + (ct0 + c) * 16 + l15] = f2bf(acc[nt][c][r]);
  __syncthreads();
#pragma unroll
  for (int i = 0; i < 4; ++i) {
    int idx = tid + i * 256;
    int nrow = idx >> 4;
    int col = (idx & 15) * 8;
    int node = base + nrow;
    if (node < N_NODES)
      *(us8*)(T + (size_t)node * HID + col) = *(const us8*)(sA + nrow * PAD + col);
  }
}

// stage A from fp32 (convert to bf16): 64 rows x 32 float4 = 2048
__device__ __forceinline__ void stage_a_f32(unsigned short* sA,
                                            const float* __restrict__ H, int base) {
#pragma unroll
  for (int i = 0; i < 8; ++i) {
    int idx = threadIdx.x + i * 256;
    int nrow = idx >> 5;
    int c4 = (idx & 31) * 4;
    float4 v = make_float4(0.f, 0.f, 0.f, 0.f);
    int node = base + nrow;
    if (node < N_NODES) v = *(const float4*)(H + (size_t)node * HID + c4);
    us4 b;
    b.x = f2bf(v.x); b.y = f2bf(v.y); b.z = f2bf(v.z); b.w = f2bf(v.w);
    *(us4*)(sA + nrow * PAD + c4) = b;
  }
}

// ---------------- mega: fill (0..783) | bounds (784) | gemm1 (785..1566) ----
// fill is atomic-chain-bound (~800k global atomics ≈ 55-58us across rounds
// 4/5/6/9 regardless of memory pattern) — gemm1 (independent of fill) hides
// under it. All-branch LDS = 17.4 KB, VGPR ~gemm's: neither binds fill's
// natural ~3 blocks/CU (round-8 failure mode removed).
__global__ __launch_bounds__(256) void mega_kernel(
    const int* __restrict__ src, const int* __restrict__ dst,
    int* __restrict__ deg, unsigned short* __restrict__ ell,
    const int* __restrict__ batch, int* __restrict__ start,
    const float* __restrict__ x, const float* __restrict__ W1,
    unsigned short* __restrict__ T) {
  __shared__ unsigned short sA[64 * PAD];   // 17.4 KB
  int b = blockIdx.x;
  if (b < FILLB) {
    // XCD-sharded degree-count + ELL fill (blockIdx%8 -> XCD round-robin);
    // NT-load the 8x-replicated dst stream so it doesn't churn L2.
    const int slice = b & 7;
    const int e0 = (b >> 3) * EPB;
    const int e1 = min(e0 + EPB, N_EDGES);
    const unsigned lo = slice * NSLICE;
    for (int e = e0 + threadIdx.x; e < e1; e += 256) {
      int d = __builtin_nontemporal_load(dst + e);
      if ((unsigned)(d - lo) < (unsigned)NSLICE) {
        int p = atomicAdd(&deg[d], 1);
        if (p < MAXDEG) ell[(d << 6) + p] = (unsigned short)src[e];
      }
    }
  } else if (b == FILLB) {
    int t = threadIdx.x;                       // graph bounds (batch sorted)
    if (t <= N_GRAPHS) {
      int lo = 0, hi = N_NODES;
      while (lo < hi) {
        int mid = (lo + hi) >> 1;
        if (batch[mid] < t) lo = mid + 1; else hi = mid;
      }
      start[t] = lo;
    }
  } else {
    const int base = (b - FILLB - 1) * 64;
    stage_a_f32(sA, x, base);
    gemm_compute_store(sA, W1, T, base);
  }
}

// ---------------- gemm layer 2: A from bf16 H ----------------
__global__ __launch_bounds__(256) void gemm_bf16_kernel(
    const unsigned short* __restrict__ Hb, const float* __restrict__ W,
    unsigned short* __restrict__ T) {
  __shared__ unsigned short sA[64 * PAD];   // 17.4 KB
  const int base = blockIdx.x * 64;
#pragma unroll
  for (int i = 0; i < 4; ++i) {        // 64 rows x 16 us8 chunks = 1024
    int idx = threadIdx.x + i * 256;
    int nrow = idx >> 4;
    int col = (idx & 15) * 8;
    us8 v = (us8)(0);
    int node = base + nrow;
    if (node < N_NODES) v = *(const us8*)(Hb + (size_t)node * HID + col);
    *(us8*)(sA + nrow * PAD + col) = v;
  }
  gemm_compute_store(sA, W, T, base);
}

// ---------------- normalized aggregation + bias + relu (bf16 ELL gather) ----
// one wave / dst node; lane owns 2 channels packed in one uint (2x bf16).
// deg_inv_sqrt on the fly; H stored bf16-packed (gemm2 rounds anyway).
__global__ __launch_bounds__(256) void aggregate_kernel(
    const unsigned int* __restrict__ Tb, const unsigned short* __restrict__ ell,
    const int* __restrict__ deg, const float* __restrict__ bias,
    unsigned int* __restrict__ Hb) {
  int node = (blockIdx.x * blockDim.x + threadIdx.x) >> 6;
  int lane = threadIdx.x & 63;
  if (node >= N_NODES) return;
  int dn = deg[node];
  float dd = rsqrtf((float)dn + 1.0f);
  float2 b = ((const float2*)bias)[lane];
  unsigned sv = Tb[(size_t)node * 64 + lane];
  float wself = dd * dd;
  float ax = __int_as_float(sv << 16) * wself;
  float ay = __int_as_float(sv & 0xffff0000u) * wself;
  int m = min(dn, MAXDEG);
  int s0 = node << 6;
  int sidx = 0; float wv = 0.f;
  if (lane < m) {
    sidx = (int)ell[s0 + lane];       // coalesced (ELL row contiguous)
    wv = rsqrtf((float)deg[sidx] + 1.0f) * dd;   // parallel gather
  }
  int j = 0;
  for (; j + 8 <= m; j += 8) {
#pragma unroll
    for (int q = 0; q < 8; ++q) {     // 8 independent row gathers in flight
      int s = __builtin_amdgcn_readlane(sidx, j + q);
      float w = __int_as_float(__builtin_amdgcn_readlane(__float_as_int(wv), j + q));
      unsigned t = Tb[(size_t)s * 64 + lane];
      ax += w * __int_as_float(t << 16);
      ay += w * __int_as_float(t & 0xffff0000u);
    }
  }
  for (; j < m; ++j) {
    int s = __builtin_amdgcn_readlane(sidx, j);
    float w = __int_as_float(__builtin_amdgcn_readlane(__float_as_int(wv), j));
    unsigned t = Tb[(size_t)s * 64 + lane];
    ax += w * __int_as_float(t << 16);
    ay += w * __int_as_float(t & 0xffff0000u);
  }
  float ox = fmaxf(ax + b.x, 0.f);
  float oy = fmaxf(ay + b.y, 0.f);
  Hb[(size_t)node * 64 + lane] =
      (unsigned)f2bf(ox) | ((unsigned)f2bf(oy) << 16);
}

// ---------------- fused pool + FC head + log_softmax: 1 block / graph -------
__global__ __launch_bounds__(256) void pool_head_kernel(
    const unsigned int* __restrict__ Hb, const int* __restrict__ start,
    const float* __restrict__ Wfc, const float* __restrict__ bfc,
    float* __restrict__ out) {
  __shared__ float2 red[4][64];
  __shared__ float spool[HID];
  int g = blockIdx.x;
  int n0 = start[g], n1 = start[g + 1];
  int lane = threadIdx.x & 63, w = threadIdx.x >> 6;
  float ax = 0.f, ay = 0.f;
  for (int n = n0 + w; n < n1; n += 4) {
    unsigned h = Hb[(size_t)n * 64 + lane];
    ax += __int_as_float(h << 16);
    ay += __int_as_float(h & 0xffff0000u);
  }
  red[w][lane] = make_float2(ax, ay);
  __syncthreads();
  if (threadIdx.x < 64) {
    float2 a = red[0][lane], b1 = red[1][lane], c = red[2][lane], d = red[3][lane];
    float inv = 1.0f / fmaxf((float)(n1 - n0), 1.0f);
    spool[lane * 2]     = (a.x + b1.x + c.x + d.x) * inv;
    spool[lane * 2 + 1] = (a.y + b1.y + c.y + d.y) * inv;
  }
  __syncthreads();
  if (threadIdx.x < 64) {
    int o = lane & 15;
    float part = 0.f;
    for (int k = (lane >> 4); k < HID; k += 4)
      part += spool[k] * Wfc[k * OUT_C + o];
    part += __shfl_xor(part, 16);
    part += __shfl_xor(part, 32);
    float logit = part + bfc[o];
    float m = logit;
#pragma unroll
    for (int d = 8; d >= 1; d >>= 1) m = fmaxf(m, __shfl_xor(m, d, 16));
    float e = __expf(logit - m);
    float s = e;
#pragma unroll
    for (int d = 8; d >= 1; d >>= 1) s += __shfl_xor(s, d, 16);
    float r = logit - m - __logf(s);
    if (lane < 16) out[g * OUT_C + o] = r;
  }
}

extern "C" void kernel_launch(void* const* d_in, const int* in_sizes, int n_in,
                              void* d_out, int out_size, void* d_ws, size_t ws_size,
                              hipStream_t stream) {
  const float* x    = (const float*)d_in[0];
  const int*   ei   = (const int*)d_in[1];
  const int*   batch= (const int*)d_in[2];
  const float* W1   = (const float*)d_in[3];
  const float* b1   = (const float*)d_in[4];
  const float* W2   = (const float*)d_in[5];
  const float* b2   = (const float*)d_in[6];
  const float* Wfc  = (const float*)d_in[7];
  const float* bfc  = (const float*)d_in[8];
  float* out = (float*)d_out;
  const int* src = ei;              // edge_index[0]
  const int* dst = ei + N_EDGES;    // edge_index[1]

  char* p = (char*)d_ws;
  auto alloc = [&](size_t bytes) { char* r = p; p += (bytes + 255) & ~255ull; return r; };
  int*   degI   = (int*)alloc((size_t)N_NODES * 4);
  int*   start  = (int*)alloc((N_GRAPHS + 1) * 4);
  unsigned short* ell = (unsigned short*)alloc((size_t)N_NODES * MAXDEG * 2); // 6.4 MB
  unsigned short* T   = (unsigned short*)alloc((size_t)N_NODES * HID * 2);    // 12.8 MB
  unsigned short* Hb  = (unsigned short*)alloc((size_t)N_NODES * HID * 2);    // 12.8 MB

  hipMemsetAsync(degI, 0, (size_t)N_NODES * 4, stream);

  int agg_blocks = (N_NODES * 64 + 255) / 256;

  mega_kernel<<<FILLB + 1 + GEMMB, 256, 0, stream>>>(src, dst, degI, ell,
                                                     batch, start, x, W1, T);
  aggregate_kernel<<<agg_blocks, 256, 0, stream>>>((const unsigned int*)T, ell, degI, b1,
                                                   (unsigned int*)Hb);
  gemm_bf16_kernel<<<GEMMB, 256, 0, stream>>>(Hb, W2, T);
  aggregate_kernel<<<agg_blocks, 256, 0, stream>>>((const unsigned int*)T, ell, degI, b2,
                                                   (unsigned int*)Hb);
  pool_head_kernel<<<N_GRAPHS, 256, 0, stream>>>((const unsigned int*)Hb, start,
                                                 Wfc, bfc, out);
}